// Round 1
// baseline (82.529 us; speedup 1.0000x reference)
//
#include <hip/hip_runtime.h>

// FIR filter: out[b,t,c] = sum_{i=0}^{F-1} w[i,c] * x[b, t+i-(F-1), c]
// (causal: taps reaching t<0 contribute zero)
// Shapes: x [B=64, T=2048, C=32] f32, w [F=16, C=32] f32, out [B,T,C] f32.
// Memory-bound: 32 MiB total traffic -> ~5 us roofline at 6.3 TB/s.

constexpr int B  = 64;
constexpr int T  = 2048;
constexpr int C  = 32;
constexpr int F  = 16;
constexpr int C4 = C / 4;  // float4 groups per timestep = 8

__global__ __launch_bounds__(256) void fir_kernel(
    const float* __restrict__ x, const float* __restrict__ w, float* __restrict__ out)
{
    const int tid = blockIdx.x * blockDim.x + threadIdx.x;   // one thread = 4 channels of one (b,t)
    const int c4  = tid & (C4 - 1);
    const int bt  = tid >> 3;            // b*T + t
    const int t   = bt & (T - 1);        // T = 2048 is pow2

    const float4* __restrict__ x4 = reinterpret_cast<const float4*>(x);
    const float4* __restrict__ w4 = reinterpret_cast<const float4*>(w);

    const int base = bt * C4 + c4;       // float4 index of (b, t, c4)

    float4 acc = make_float4(0.f, 0.f, 0.f, 0.f);
#pragma unroll
    for (int i = 0; i < F; ++i) {
        const int ti = t + i - (F - 1);  // timestep this tap reads
        if (ti >= 0) {                   // zero-pad region: skip (uniform except t<15)
            const float4 xv = x4[base + (i - (F - 1)) * C4];
            const float4 wv = w4[i * C4 + c4];
            acc.x = fmaf(wv.x, xv.x, acc.x);
            acc.y = fmaf(wv.y, xv.y, acc.y);
            acc.z = fmaf(wv.z, xv.z, acc.z);
            acc.w = fmaf(wv.w, xv.w, acc.w);
        }
    }
    reinterpret_cast<float4*>(out)[base] = acc;
}

extern "C" void kernel_launch(void* const* d_in, const int* in_sizes, int n_in,
                              void* d_out, int out_size, void* d_ws, size_t ws_size,
                              hipStream_t stream)
{
    const float* x = (const float*)d_in[0];   // [B, T, C] f32
    const float* w = (const float*)d_in[1];   // [F, C]    f32
    float* out     = (float*)d_out;           // [B, T, C] f32

    const int total_threads = B * T * C4;     // 1,048,576
    const int block = 256;
    fir_kernel<<<total_threads / block, block, 0, stream>>>(x, w, out);
}

// Round 2
// 75.193 us; speedup vs baseline: 1.0976x; 1.0976x over previous
//
#include <hip/hip_runtime.h>

// Causal per-channel FIR: out[b,t,c] = sum_{i=0}^{F-1} w[i,c] * x[b, t+i-(F-1), c]
// x [B=64, T=2048, C=32] f32, w [F=16, C=32] f32, out = x.shape f32.
// Memory-bound: 33.5 MB total ideal traffic -> ~5.3 us @ 6.3 TB/s.
//
// Each thread: 4 channels (one float4) x TT=4 consecutive timesteps.
// Loads the 19-deep x window into registers once; 16 tap-weights CSE'd
// across the 4 outputs. 3.4x fewer load instructions than 1-t-per-thread.

constexpr int B  = 64;
constexpr int T  = 2048;
constexpr int C  = 32;
constexpr int F  = 16;
constexpr int C4 = C / 4;     // 8 float4 groups per timestep
constexpr int TT = 4;         // timesteps per thread
constexpr int NT = T / TT;    // 512 tiles per batch row

__global__ __launch_bounds__(256) void fir_kernel(
    const float* __restrict__ x, const float* __restrict__ w, float* __restrict__ out)
{
    const int tid  = blockIdx.x * blockDim.x + threadIdx.x;
    const int c4   = tid & (C4 - 1);
    const int bt   = tid >> 3;          // b*NT + tile
    const int tile = bt & (NT - 1);
    const int b    = bt >> 9;           // NT = 512
    const int t0   = tile * TT;

    const float4* __restrict__ x4 = reinterpret_cast<const float4*>(x);
    const float4* __restrict__ w4 = reinterpret_cast<const float4*>(w);
    float4*       __restrict__ o4 = reinterpret_cast<float4*>(out);

    const int base = (b * T + t0) * C4 + c4;   // float4 index of (b, t0, c4)

    // Register window: x[b, t0-15 .. t0+TT-1, c4]  (zeros where t < 0)
    float4 win[TT + F - 1];
#pragma unroll
    for (int j = 0; j < TT + F - 1; ++j) {
        const int ti = t0 + j - (F - 1);
        if (ti >= 0) {
            win[j] = x4[base + (j - (F - 1)) * C4];
        } else {
            win[j] = make_float4(0.f, 0.f, 0.f, 0.f);
        }
    }

#pragma unroll
    for (int t = 0; t < TT; ++t) {
        float4 acc = make_float4(0.f, 0.f, 0.f, 0.f);
#pragma unroll
        for (int i = 0; i < F; ++i) {
            const float4 wv = w4[i * C4 + c4];   // CSE'd across t by compiler
            const float4 xv = win[t + i];
            acc.x = fmaf(wv.x, xv.x, acc.x);
            acc.y = fmaf(wv.y, xv.y, acc.y);
            acc.z = fmaf(wv.z, xv.z, acc.z);
            acc.w = fmaf(wv.w, xv.w, acc.w);
        }
        o4[base + t * C4] = acc;
    }
}

extern "C" void kernel_launch(void* const* d_in, const int* in_sizes, int n_in,
                              void* d_out, int out_size, void* d_ws, size_t ws_size,
                              hipStream_t stream)
{
    const float* x = (const float*)d_in[0];   // [B, T, C] f32
    const float* w = (const float*)d_in[1];   // [F, C]    f32
    float* o       = (float*)d_out;           // [B, T, C] f32

    const int total_threads = B * NT * C4;    // 64*512*8 = 262144
    const int block = 256;
    fir_kernel<<<total_threads / block, block, 0, stream>>>(x, w, o);
}

// Round 3
// 72.442 us; speedup vs baseline: 1.1392x; 1.0380x over previous
//
#include <hip/hip_runtime.h>

// Causal per-channel FIR: out[b,t,c] = sum_{i=0}^{F-1} w[i,c] * x[b, t+i-(F-1), c]
// x [B=64, T=2048, C=32] f32, w [F=16, C=32] f32, out = x.shape f32.
// Memory-bound: 33.5 MB ideal traffic -> ~5.3 us @ 6.3 TB/s. dur_us additionally
// carries ~65 us of harness reset fills (268 MB ws poison etc.) we cannot avoid.
//
// TT=8 timesteps per thread: 23-deep float4 register window -> 2.9 loads/output.
// Tap-outer loop keeps ONE weight float4 live while accumulating into 8 accs.
// Boundary (t0 < F-1) handled in a separate rarely-taken path so the hot path
// has zero compares.

constexpr int B  = 64;
constexpr int T  = 2048;
constexpr int C  = 32;
constexpr int F  = 16;
constexpr int C4 = C / 4;     // 8 float4 groups per timestep
constexpr int TT = 8;         // timesteps per thread
constexpr int NT = T / TT;    // 256 tiles per batch row
constexpr int W  = TT + F - 1; // 23-deep window

__global__ __launch_bounds__(256) void fir_kernel(
    const float* __restrict__ x, const float* __restrict__ w, float* __restrict__ out)
{
    const int tid  = blockIdx.x * blockDim.x + threadIdx.x;
    const int c4   = tid & (C4 - 1);
    const int bt   = tid >> 3;          // b*NT + tile
    const int tile = bt & (NT - 1);
    const int b    = bt >> 8;           // NT = 256
    const int t0   = tile * TT;

    const float4* __restrict__ x4 = reinterpret_cast<const float4*>(x);
    const float4* __restrict__ w4 = reinterpret_cast<const float4*>(w);
    float4*       __restrict__ o4 = reinterpret_cast<float4*>(out);

    const int base = (b * T + t0) * C4 + c4;   // float4 index of (b, t0, c4)

    // Register window: x[b, t0-15 .. t0+TT-1, c4]  (zeros where t < 0)
    float4 win[W];
    if (t0 >= F - 1) {
        // Hot path: whole window in-bounds, no compares.
#pragma unroll
        for (int j = 0; j < W; ++j)
            win[j] = x4[base + (j - (F - 1)) * C4];
    } else {
        // First tile of each batch row only.
#pragma unroll
        for (int j = 0; j < W; ++j) {
            const int ti = t0 + j - (F - 1);
            win[j] = (ti >= 0) ? x4[base + (j - (F - 1)) * C4]
                               : make_float4(0.f, 0.f, 0.f, 0.f);
        }
    }

    float4 acc[TT];
#pragma unroll
    for (int t = 0; t < TT; ++t) acc[t] = make_float4(0.f, 0.f, 0.f, 0.f);

    // Tap-outer: one weight vector live at a time, 8 independent FMA chains.
#pragma unroll
    for (int i = 0; i < F; ++i) {
        const float4 wv = w4[i * C4 + c4];
#pragma unroll
        for (int t = 0; t < TT; ++t) {
            const float4 xv = win[t + i];
            acc[t].x = fmaf(wv.x, xv.x, acc[t].x);
            acc[t].y = fmaf(wv.y, xv.y, acc[t].y);
            acc[t].z = fmaf(wv.z, xv.z, acc[t].z);
            acc[t].w = fmaf(wv.w, xv.w, acc[t].w);
        }
    }

#pragma unroll
    for (int t = 0; t < TT; ++t)
        o4[base + t * C4] = acc[t];
}

extern "C" void kernel_launch(void* const* d_in, const int* in_sizes, int n_in,
                              void* d_out, int out_size, void* d_ws, size_t ws_size,
                              hipStream_t stream)
{
    const float* x = (const float*)d_in[0];   // [B, T, C] f32
    const float* w = (const float*)d_in[1];   // [F, C]    f32
    float* o       = (float*)d_out;           // [B, T, C] f32

    const int total_threads = B * NT * C4;    // 64*256*8 = 131072
    const int block = 256;
    fir_kernel<<<total_threads / block, block, 0, stream>>>(x, w, o);
}